// Round 3
// baseline (95.864 us; speedup 1.0000x reference)
//
#include <hip/hip_runtime.h>
#include <math.h>

#define NS    32768          // samples per sequence
#define NB    128            // interpolation bins
#define NSEQ  128            // 16 batches * 8 heads
#define TPB1  256            // phase-1: one block per sequence, thread = 128-sample chunk
#define NPART 32             // phase-2 parts per sequence
#define PART  (NS / NPART)   // 1024 samples
#define TPB2  256            // phase-2 threads; CH=4 samples/thread
#define CH    4

__device__ __forceinline__ float fsin(double x) {
    // sin(x) via f64 range reduction to revolutions + v_sin_f32
    double u = x * 0.15915494309189533576888376337251;  // 1/(2*pi)
    double f = u - rint(u);                              // [-0.5, 0.5]
    return __builtin_amdgcn_sinf((float)f);              // sin(2*pi*f)
}

// segment params for a chunk starting at sample ci0 (chunk never crosses a segment)
__device__ __forceinline__ void seg_params(int ci0, int& lo, int& hi,
                                           double& w0, double& wst) {
    if (ci0 < 128)            { lo = 0;   hi = 1;   w0 = 0.0; wst = 0.0; }
    else if (ci0 >= NS - 128) { lo = 127; hi = 127; w0 = 0.0; wst = 0.0; }
    else {
        lo = (ci0 - 128) >> 8;  hi = lo + 1;
        int off = (ci0 - 128) & 255;
        w0 = (off + 0.5) * (1.0 / 256.0);
        wst = 1.0 / 256.0;
    }
}

// ---------------- phase 1: bins + part-boundary accumulators -----------------
// wacc: [seq][NPART][3] exclusive prefixes {cs1, cs3, cs2} at sample p*PART
// wbins: [seq][6][128] f64 bins {amp, f0, mix, std, modf, b}
__global__ __launch_bounds__(TPB1)
void pre_kernel(const float* __restrict__ xg, const float* __restrict__ ng,
                double* __restrict__ wacc, double* __restrict__ wbins) {
    __shared__ double bins[6][NB];
    __shared__ double lred[TPB1 / 64][3];

    const double PI_  = 3.14159265358979323846;
    const double MINF = 40.0 / 11025.0;
    const double FRNG = (4000.0 - 40.0) / 11025.0;

    int s    = blockIdx.x;
    int tid  = threadIdx.x;
    int lane = tid & 63;
    int wid  = tid >> 6;

    // bins in f64 -> LDS + global
    const float* xs = xg + s * 10 * 128;
    double* gb = wbins + (size_t)s * 6 * NB;
    for (int idx = tid; idx < 6 * NB; idx += TPB1) {
        int q = idx >> 7, j = idx & 127;
        double v;
        if (q == 0) {
            double a0 = (double)xs[j], a1 = (double)xs[128 + j];
            v = sqrt(a0 * a0 + a1 * a1);
        } else {
            int c = (q - 1) * 2;
            double yy = (double)xs[(c + 1) * 128 + j];
            double xx = (double)xs[c * 128 + j];
            double ang = atan2(yy, xx) / PI_;
            double sh, sc;
            if      (q == 1) { sh = MINF; sc = FRNG; }   // f0
            else if (q == 2) { sh = 1.0;  sc = 0.5;  }   // mix
            else if (q == 3) { sh = MINF; sc = FRNG; }   // noise_std
            else if (q == 4) { sh = 0.25; sc = 4.75; }   // mod_factor
            else             { sh = 0.1;  sc = 9.9;  }   // b
            v = sh + ang * sc;
        }
        bins[q][j] = v;
        gb[q * NB + j] = v;
    }
    __syncthreads();

    // thread = 128-sample chunk c; totals (t1, t3, t2) in closed form
    int c   = tid;
    int ci0 = c * 128;
    int lo, hi; double w0, wst;
    seg_params(ci0, lo, hi, w0, wst);
    double f0L = bins[1][lo], dF0 = bins[1][hi] - f0L;
    double stL = bins[3][lo], dSt = bins[3][hi] - stL;
    double mfL = bins[4][lo], dMf = bins[4][hi] - mfL;

    const float4* nn4 = reinterpret_cast<const float4*>(ng + (size_t)s * NS + ci0);
    double S0 = 0.0, S1 = 0.0;
    #pragma unroll
    for (int q4 = 0; q4 < 32; ++q4) {
        float4 nv = nn4[q4];
        double jd = (double)(q4 * 4);
        S0 += (double)nv.x; S1 += jd * (double)nv.x;
        S0 += (double)nv.y; S1 += (jd + 1.0) * (double)nv.y;
        S0 += (double)nv.z; S1 += (jd + 2.0) * (double)nv.z;
        S0 += (double)nv.w; S1 += (jd + 3.0) * (double)nv.w;
    }
    double sw = 128.0 * w0 + wst * 8128.0;          // sum of w over 128 samples
    double t3 = 128.0 * f0L + dF0 * sw;
    double t2 = 128.0 * mfL + dMf * sw;
    double t1 = t3 + stL * S0 + dSt * (w0 * S0 + wst * S1);

    // block inclusive scan (wave shfl + LDS wave totals)
    double v1 = t1, v3 = t3, v2 = t2;
    #pragma unroll
    for (int d = 1; d < 64; d <<= 1) {
        double u1 = __shfl_up(v1, d);
        double u3 = __shfl_up(v3, d);
        double u2 = __shfl_up(v2, d);
        if (lane >= d) { v1 += u1; v3 += u3; v2 += u2; }
    }
    if (lane == 63) { lred[wid][0] = v1; lred[wid][1] = v3; lred[wid][2] = v2; }
    __syncthreads();
    double b1 = 0.0, b3 = 0.0, b2 = 0.0;
    #pragma unroll
    for (int k = 0; k < TPB1 / 64 - 1; ++k)
        if (wid > k) { b1 += lred[k][0]; b3 += lred[k][1]; b2 += lred[k][2]; }

    // exclusive prefix at chunk start; record at part boundaries (every 8 chunks)
    if ((c & 7) == 0) {
        double* A = wacc + ((size_t)s * NPART + (c >> 3)) * 3;
        A[0] = b1 + (v1 - t1);
        A[1] = b3 + (v3 - t3);
        A[2] = b2 + (v2 - t2);
    }
}

// ---------------- phase 2: main synth, 8 heads fused per block ---------------
__global__ __launch_bounds__(TPB2)
void fm_main_kernel(const float* __restrict__ ng, const double* __restrict__ wacc,
                    const double* __restrict__ wbins, float* __restrict__ out) {
    __shared__ double lbins[8][6][NB];   // 48 KB
    __shared__ double lred[TPB2 / 64][3];

    int bx   = blockIdx.x;
    int b    = bx >> 5;          // batch
    int p    = bx & (NPART - 1); // part
    int tid  = threadIdx.x;
    int lane = tid & 63;
    int wid  = tid >> 6;

    // stage all 8 heads' bins (contiguous 48 KB region, coalesced)
    const double* gb = wbins + (size_t)b * 8 * 6 * NB;
    double* lb = &lbins[0][0][0];
    for (int idx = tid; idx < 8 * 6 * NB; idx += TPB2) lb[idx] = gb[idx];
    __syncthreads();

    int i0 = p * PART + tid * CH;
    int lo, hi; double w0, wst;
    seg_params(i0, lo, hi, w0, wst);

    float acc[CH] = {0.f, 0.f, 0.f, 0.f};

    for (int h = 0; h < 8; ++h) {
        int s = b * 8 + h;
        const double* B = &lbins[h][0][0];
        double amL = B[0 * NB + lo], dAm = B[0 * NB + hi] - amL;
        double f0L = B[1 * NB + lo], dF0 = B[1 * NB + hi] - f0L;
        double mxL = B[2 * NB + lo], dMx = B[2 * NB + hi] - mxL;
        double stL = B[3 * NB + lo], dSt = B[3 * NB + hi] - stL;
        double mfL = B[4 * NB + lo], dMf = B[4 * NB + hi] - mfL;
        double bL  = B[5 * NB + lo], dB  = B[5 * NB + hi] - bL;

        float4 nv = *reinterpret_cast<const float4*>(ng + (size_t)s * NS + i0);
        double n0 = (double)nv.x, n1 = (double)nv.y, n2 = (double)nv.z, n3 = (double)nv.w;
        double S0 = n0 + n1 + n2 + n3;
        double S1 = n1 + 2.0 * n2 + 3.0 * n3;

        double sw = 4.0 * w0 + wst * 6.0;
        double T3 = 4.0 * f0L + dF0 * sw;
        double T2 = 4.0 * mfL + dMf * sw;
        double T1 = T3 + stL * S0 + dSt * (w0 * S0 + wst * S1);

        // block inclusive scan of (T1, T3, T2)
        double v1 = T1, v3 = T3, v2 = T2;
        #pragma unroll
        for (int d = 1; d < 64; d <<= 1) {
            double u1 = __shfl_up(v1, d);
            double u3 = __shfl_up(v3, d);
            double u2 = __shfl_up(v2, d);
            if (lane >= d) { v1 += u1; v3 += u3; v2 += u2; }
        }
        if (lane == 63) { lred[wid][0] = v1; lred[wid][1] = v3; lred[wid][2] = v2; }
        __syncthreads();
        double b1 = 0.0, b3 = 0.0, b2 = 0.0;
        #pragma unroll
        for (int k = 0; k < TPB2 / 64 - 1; ++k)
            if (wid > k) { b1 += lred[k][0]; b3 += lred[k][1]; b2 += lred[k][2]; }
        __syncthreads();   // lred safe to overwrite next h

        const double* A = wacc + ((size_t)s * NPART + p) * 3;
        double a1 = A[0] + b1 + (v1 - T1);
        double a3 = A[1] + b3 + (v3 - T3);
        double a2 = A[2] + b2 + (v2 - T2);

        float nf[CH] = {nv.x, nv.y, nv.z, nv.w};
        double w = w0;
        #pragma unroll
        for (int j = 0; j < CH; ++j) {
            double nd  = (double)nf[j];
            double f0v = f0L + w * dF0;
            double stv = stL + w * dSt;
            double mfv = mfL + w * dMf;
            a1 += f0v + nd * stv;   // cs1
            a3 += f0v;              // cs3
            a2 += mfv;              // cs2
            double ampv = amL + w * dAm;
            double mixv = mxL + w * dMx;
            double bv   = bL  + w * dB;
            double harm = ampv * mixv;
            double namp = ampv * (1.0 - mixv);
            float s1 = fsin(a1);
            float s2 = fsin(a2);
            float s3 = fsin(a3 + bv * (double)s2);
            acc[j] += (float)namp * s1 + (float)harm * s3;
            w += wst;
        }
    }

    float4 o = make_float4(acc[0] * 0.125f, acc[1] * 0.125f,
                           acc[2] * 0.125f, acc[3] * 0.125f);
    *reinterpret_cast<float4*>(out + (size_t)b * NS + i0) = o;
}

extern "C" void kernel_launch(void* const* d_in, const int* in_sizes, int n_in,
                              void* d_out, int out_size, void* d_ws, size_t ws_size,
                              hipStream_t stream) {
    const float* x     = (const float*)d_in[0];
    const float* noise = (const float*)d_in[1];
    float* out = (float*)d_out;
    // ws layout: accs [128][32][3] doubles (96 KB), then bins [128][6][128] doubles (768 KB)
    double* wacc  = (double*)d_ws;
    double* wbins = wacc + (size_t)NSEQ * NPART * 3;
    pre_kernel<<<NSEQ, TPB1, 0, stream>>>(x, noise, wacc, wbins);
    fm_main_kernel<<<16 * NPART, TPB2, 0, stream>>>(noise, wacc, wbins, out);
}

// Round 4
// 81.374 us; speedup vs baseline: 1.1781x; 1.1781x over previous
//
#include <hip/hip_runtime.h>
#include <math.h>

#define NS    32768              // samples per sequence
#define NB    128                // interpolation bins
#define NSEQ  128                // 16 batches * 8 heads
#define CELL  16                 // accumulator granularity (never crosses a segment)
#define NCELL (NS / CELL)        // 2048 cells per sequence
#define TPB1  1024
#define RUN   (NS / TPB1)        // 32 samples (2 cells) per phase-1 thread
#define TPB2  256
#define GRID2 (16 * NCELL * 8 / TPB2)   // 1024 blocks

// sin(2*pi*x) — v_sin_f32 takes revolutions; reduce to [-0.5, 0.5] first
__device__ __forceinline__ float sinr(float x) {
    return __builtin_amdgcn_sinf(x - rintf(x));
}

// segment params for a 16/32-aligned chunk starting at sample i (clamp regions
// and segment boundaries are all multiples of 32, so chunks never straddle)
__device__ __forceinline__ void seg_params(int i, int& lo, int& hi,
                                           double& w0, double& wst) {
    if (i < 128)            { lo = 0;   hi = 1;   w0 = 0.0; wst = 0.0; }
    else if (i >= NS - 128) { lo = 127; hi = 127; w0 = 0.0; wst = 0.0; }
    else {
        lo = (i - 128) >> 8;  hi = lo + 1;
        int off = (i - 128) & 255;
        w0 = (off + 0.5) * (1.0 / 256.0);
        wst = 1.0 / 256.0;
    }
}

// ---- phase 1: bins (f32, phase streams in revolutions) + exclusive f64
//      prefix triples {cs1, cs3, cs2} at every 16-sample cell boundary
__global__ __launch_bounds__(TPB1)
void pre_kernel(const float* __restrict__ xg, const float* __restrict__ ng,
                double* __restrict__ wacc, float* __restrict__ wbins) {
    __shared__ double bf0[NB], bst[NB], bmf[NB];   // f64 copies of phase streams
    __shared__ double lred[TPB1 / 64][3];

    const double PI_    = 3.14159265358979323846;
    const double INV2PI = 0.15915494309189533576888376337251;
    const double MINF   = 40.0 / 11025.0;
    const double FRNG   = (4000.0 - 40.0) / 11025.0;

    int s    = blockIdx.x;
    int tid  = threadIdx.x;
    int lane = tid & 63;
    int wid  = tid >> 6;

    const float* xs = xg + s * 10 * NB;
    if (tid < 6 * NB) {
        int q = tid >> 7, j = tid & 127;
        double v;
        if (q == 0) {
            double a0 = (double)xs[j], a1 = (double)xs[NB + j];
            v = sqrt(a0 * a0 + a1 * a1);
        } else {
            int c2 = (q - 1) * 2;
            double ang = atan2((double)xs[(c2 + 1) * NB + j],
                               (double)xs[c2 * NB + j]) / PI_;
            double sh, sc;
            if      (q == 1) { sh = MINF; sc = FRNG; }   // f0
            else if (q == 2) { sh = 1.0;  sc = 0.5;  }   // mix (amplitude)
            else if (q == 3) { sh = MINF; sc = FRNG; }   // noise_std
            else if (q == 4) { sh = 0.25; sc = 4.75; }   // mod_factor
            else             { sh = 0.1;  sc = 9.9;  }   // b
            v = sh + ang * sc;
            if (q != 2) v *= INV2PI;   // phase streams + b -> revolutions
        }
        wbins[s * (6 * NB) + tid] = (float)v;
        if      (q == 1) bf0[j] = v;
        else if (q == 3) bst[j] = v;
        else if (q == 4) bmf[j] = v;
    }
    __syncthreads();

    // thread = 32-sample run = 2 cells; closed-form cell totals
    int ci = tid * RUN;
    int lo, hi; double w0, wst;
    seg_params(ci, lo, hi, w0, wst);
    double f0L = bf0[lo], dF0 = bf0[hi] - f0L;
    double stL = bst[lo], dSt = bst[hi] - stL;
    double mfL = bmf[lo], dMf = bmf[hi] - mfL;

    const float4* nn4 = reinterpret_cast<const float4*>(ng + (size_t)s * NS + ci);
    double t1c[2], t3c[2], t2c[2];
    #pragma unroll
    for (int c = 0; c < 2; ++c) {
        double S0 = 0.0, S1 = 0.0;
        #pragma unroll
        for (int q4 = 0; q4 < 4; ++q4) {
            float4 nv = nn4[c * 4 + q4];
            double jd = (double)(q4 * 4);
            S0 += (double)nv.x; S1 += jd * (double)nv.x;
            S0 += (double)nv.y; S1 += (jd + 1.0) * (double)nv.y;
            S0 += (double)nv.z; S1 += (jd + 2.0) * (double)nv.z;
            S0 += (double)nv.w; S1 += (jd + 3.0) * (double)nv.w;
        }
        double wc = w0 + (double)(c * 16) * wst;
        double sw = 16.0 * wc + wst * 120.0;          // sum of w over 16 samples
        double t3 = 16.0 * f0L + dF0 * sw;
        double t2 = 16.0 * mfL + dMf * sw;
        double t1 = t3 + stL * S0 + dSt * (wc * S0 + wst * S1);
        t1c[c] = t1; t3c[c] = t3; t2c[c] = t2;
    }
    double r1 = t1c[0] + t1c[1], r3 = t3c[0] + t3c[1], r2 = t2c[0] + t2c[1];

    // block inclusive scan of run totals
    double v1 = r1, v3 = r3, v2 = r2;
    #pragma unroll
    for (int d = 1; d < 64; d <<= 1) {
        double u1 = __shfl_up(v1, d);
        double u3 = __shfl_up(v3, d);
        double u2 = __shfl_up(v2, d);
        if (lane >= d) { v1 += u1; v3 += u3; v2 += u2; }
    }
    if (lane == 63) { lred[wid][0] = v1; lred[wid][1] = v3; lred[wid][2] = v2; }
    __syncthreads();
    double b1 = 0.0, b3 = 0.0, b2 = 0.0;
    for (int k = 0; k < wid; ++k) {
        b1 += lred[k][0]; b3 += lred[k][1]; b2 += lred[k][2];
    }
    double e1 = b1 + v1 - r1, e3 = b3 + v3 - r3, e2 = b2 + v2 - r2;

    double* A = wacc + ((size_t)s * NCELL + (size_t)tid * 2) * 3;
    A[0] = e1;          A[1] = e3;          A[2] = e2;
    A[3] = e1 + t1c[0]; A[4] = e3 + t3c[0]; A[5] = e2 + t2c[0];
}

// ---- phase 2: zero barriers/scans; thread = (cell, head); shfl head-mean
__global__ __launch_bounds__(TPB2)
void fm2_kernel(const float* __restrict__ ng, const double* __restrict__ wacc,
                const float* __restrict__ wbins, float* __restrict__ out) {
    int g  = blockIdx.x * TPB2 + threadIdx.x;
    int h  = g & 7;                 // head (lanes 8k..8k+7 share a cell)
    int q  = g >> 3;                // global cell slot [0, 16*2048)
    int b  = q >> 11;               // batch
    int c  = q & (NCELL - 1);       // cell within sequence
    int s  = (b << 3) + h;
    int i0 = c << 4;

    int lo, hi; double w0d, wstd;
    seg_params(i0, lo, hi, w0d, wstd);
    float w0  = (float)w0d;
    float wsf = (float)wstd;

    const float* B = wbins + s * (6 * NB);
    float amL = B[lo],          dAm = B[hi] - amL;
    float f0L = B[NB + lo],     dF0 = B[NB + hi] - f0L;
    float mxL = B[2 * NB + lo], dMx = B[2 * NB + hi] - mxL;
    float stL = B[3 * NB + lo], dSt = B[3 * NB + hi] - stL;
    float mfL = B[4 * NB + lo], dMf = B[4 * NB + hi] - mfL;
    float bbL = B[5 * NB + lo], dBb = B[5 * NB + hi] - bbL;

    // exact f64 anchors -> f32 fractional revolutions (once per thread)
    const double* A = wacc + ((size_t)s * NCELL + c) * 3;
    double a1 = A[0], a3 = A[1], a2 = A[2];
    float fr1 = (float)(a1 - rint(a1));
    float fr3 = (float)(a3 - rint(a3));
    float fr2 = (float)(a2 - rint(a2));

    const float4* nn4 = reinterpret_cast<const float4*>(ng + (size_t)s * NS + i0);
    float4 nv0 = nn4[0], nv1 = nn4[1], nv2 = nn4[2], nv3 = nn4[3];
    float nf[CELL] = {nv0.x, nv0.y, nv0.z, nv0.w, nv1.x, nv1.y, nv1.z, nv1.w,
                      nv2.x, nv2.y, nv2.z, nv2.w, nv3.x, nv3.y, nv3.z, nv3.w};

    float arr[CELL];
    float d1 = 0.f, d2 = 0.f, d3 = 0.f;
    #pragma unroll
    for (int j = 0; j < CELL; ++j) {
        float wf  = fmaf((float)j, wsf, w0);
        float f0v = fmaf(wf, dF0, f0L);
        float stv = fmaf(wf, dSt, stL);
        float mfv = fmaf(wf, dMf, mfL);
        d3 += f0v;                       // cs3 (revolutions, rel. to anchor)
        d1 += fmaf(nf[j], stv, f0v);     // cs1
        d2 += mfv;                       // cs2
        float ampv = fmaf(wf, dAm, amL);
        float mixv = fmaf(wf, dMx, mxL);
        float bv   = fmaf(wf, dBb, bbL);
        float s2 = sinr(fr2 + d2);
        float s1 = sinr(fr1 + d1);
        float s3 = sinr(fmaf(bv, s2, fr3 + d3));
        float harm = ampv * mixv;
        arr[j] = fmaf(harm, s3, (ampv - harm) * s1);
    }

    // head-mean: butterfly over the 3 low lane bits
    #pragma unroll
    for (int m = 1; m <= 4; m <<= 1) {
        #pragma unroll
        for (int j = 0; j < CELL; ++j) arr[j] += __shfl_xor(arr[j], m);
    }
    if (h == 0) {
        float4* op = reinterpret_cast<float4*>(out + (size_t)b * NS + i0);
        #pragma unroll
        for (int j4 = 0; j4 < 4; ++j4)
            op[j4] = make_float4(arr[j4 * 4 + 0] * 0.125f, arr[j4 * 4 + 1] * 0.125f,
                                 arr[j4 * 4 + 2] * 0.125f, arr[j4 * 4 + 3] * 0.125f);
    }
}

extern "C" void kernel_launch(void* const* d_in, const int* in_sizes, int n_in,
                              void* d_out, int out_size, void* d_ws, size_t ws_size,
                              hipStream_t stream) {
    const float* x     = (const float*)d_in[0];
    const float* noise = (const float*)d_in[1];
    float* out = (float*)d_out;
    // ws: wacc [128][2048][3] f64 (6.29 MB), then wbins [128][6][128] f32 (393 KB)
    double* wacc = (double*)d_ws;
    float* wbins = (float*)(wacc + (size_t)NSEQ * NCELL * 3);
    pre_kernel<<<NSEQ, TPB1, 0, stream>>>(x, noise, wacc, wbins);
    fm2_kernel<<<GRID2, TPB2, 0, stream>>>(noise, wacc, wbins, out);
}